// Round 1
// baseline (190.849 us; speedup 1.0000x reference)
//
#include <hip/hip_runtime.h>

typedef short bf16x8 __attribute__((ext_vector_type(8)));
typedef float f32x4 __attribute__((ext_vector_type(4)));
typedef unsigned int u32x4 __attribute__((ext_vector_type(4)));
typedef unsigned short u16x4 __attribute__((ext_vector_type(4)));

__device__ __forceinline__ unsigned short f2bf(float f) {
  unsigned u = __builtin_bit_cast(unsigned, f);
  u = (u + 0x7FFFu + ((u >> 16) & 1u)) >> 16;   // RNE bf16
  return (unsigned short)u;
}

// ---------------- Kernel P: partial pooling sums + x -> bf16 cast ----------
// grid (16 slices, 32 samples), 256 threads. Each block: 256 pixels.
__global__ __launch_bounds__(256) void k_pool_cvt(const float* __restrict__ x,
                                                  unsigned short* __restrict__ xb,
                                                  float* __restrict__ pp) {
  const int slice = blockIdx.x;       // 0..15
  const int b = blockIdx.y;           // 0..31
  const int t = threadIdx.x;
  const int c4 = (t & 31) * 4;        // 4-channel group
  const int seg = t >> 5;             // 0..7, 32 pixels each
  const size_t base = ((size_t)b * 4096 + slice * 256 + seg * 32) * 128;
  const float* xp = x + base;
  unsigned short* xbp = xb + base;
  f32x4 s = {0.f, 0.f, 0.f, 0.f};
  for (int p = 0; p < 32; ++p) {
    f32x4 v = *(const f32x4*)(xp + p * 128 + c4);
    s += v;
    u16x4 h;
    h.x = f2bf(v.x); h.y = f2bf(v.y); h.z = f2bf(v.z); h.w = f2bf(v.w);
    *(u16x4*)(xbp + p * 128 + c4) = h;
  }
  __shared__ f32x4 red[256];
  red[t] = s;
  __syncthreads();
  if (t < 32) {
    f32x4 tot = red[t];
#pragma unroll
    for (int g = 1; g < 8; ++g) tot += red[g * 32 + t];
    *(f32x4*)(pp + (size_t)(b * 16 + slice) * 128 + t * 4) = tot;
  }
}

// ---------------- Kernel R: finish pool, attention softmax, fused BN bias --
// grid 32 (samples), 128 threads.
__global__ __launch_bounds__(128) void k_route(const float* __restrict__ pp,
    const float* __restrict__ redk, const float* __restrict__ attk,
    const float* __restrict__ bias, const float* __restrict__ bns,
    const float* __restrict__ bnb, const float* __restrict__ bnm,
    const float* __restrict__ bnv,
    float* __restrict__ att_ws, float* __restrict__ beta_ws,
    float* __restrict__ alpha_ws) {
  const int b = blockIdx.x, t = threadIdx.x;
  __shared__ float pool[128];
  __shared__ float att[4];
  {
    float s = 0.f;
    for (int i = 0; i < 16; ++i) s += pp[(size_t)(b * 16 + i) * 128 + t];
    pool[t] = s * (1.f / 4096.f);
  }
  __syncthreads();
  if (t == 0) {
    float pr[4];
    for (int r = 0; r < 4; ++r) {
      float s = 0.f;
      for (int c = 0; c < 128; ++c) s += pool[c] * redk[c * 4 + r];
      pr[r] = fmaxf(s, 0.f);
    }
    float lgt[4]; float mx = -1e30f;
    for (int k = 0; k < 4; ++k) {
      float s = 0.f;
      for (int r = 0; r < 4; ++r) s += pr[r] * attk[r * 4 + k];
      lgt[k] = s * (1.f / 30.f);
      mx = fmaxf(mx, lgt[k]);
    }
    float den = 0.f;
    for (int k = 0; k < 4; ++k) { lgt[k] = expf(lgt[k] - mx); den += lgt[k]; }
    for (int k = 0; k < 4; ++k) { att[k] = lgt[k] / den; att_ws[b * 4 + k] = att[k]; }
  }
  __syncthreads();
  {
    float bm = 0.f;
    for (int k = 0; k < 4; ++k) bm += att[k] * bias[k * 128 + t];
    const float inv = bns[t] * rsqrtf(bnv[t] + 1e-5f);
    beta_ws[b * 128 + t] = (bm - bnm[t]) * inv + bnb[t];
    alpha_ws[t] = inv;   // sample-independent; all blocks write same value
  }
}

// ---------------- Kernel W: mix expert kernels, store transposed bf16 ------
// grid (9 taps, 32 samples), 256 threads. w_ws[b][tap][f][c] = sum_k att*ck[k][tap][c][f]
__global__ __launch_bounds__(256) void k_mixw(const float* __restrict__ ck,
                                              const float* __restrict__ att_ws,
                                              unsigned short* __restrict__ w_ws) {
  const int tap = blockIdx.x;   // 0..8
  const int b = blockIdx.y;
  const float a0 = att_ws[b * 4 + 0], a1 = att_ws[b * 4 + 1];
  const float a2 = att_ws[b * 4 + 2], a3 = att_ws[b * 4 + 3];
  const float* ckp = ck + (size_t)tap * 16384;
  unsigned short* wp = w_ws + ((size_t)b * 9 + tap) * 16384;
  for (int idx = threadIdx.x; idx < 16384; idx += 256) {
    const int c = idx & 127, f = idx >> 7;
    const size_t o = (size_t)c * 128 + f;
    float v = a0 * ckp[o] + a1 * ckp[o + 147456] + a2 * ckp[o + 2 * 147456]
            + a3 * ckp[o + 3 * 147456];
    wp[f * 128 + c] = f2bf(v);
  }
}

// ---------------- Kernel C: 3x3 conv as 9 shifted MFMA GEMMs ---------------
// grid (32 row-pair tiles, 32 samples), 256 threads = 4 waves (2x2).
// Block tile: M=128 pixels (2 image rows) x N=128 filters, K-loop 9 taps x 128 ch.
__global__ __launch_bounds__(256) void k_conv(const unsigned short* __restrict__ xb,
                                              const unsigned short* __restrict__ w_ws,
                                              const float* __restrict__ alpha_ws,
                                              const float* __restrict__ beta_ws,
                                              float* __restrict__ out) {
  const int tile = blockIdx.x;   // 0..31 (row pair)
  const int b = blockIdx.y;      // sample
  const int t = threadIdx.x;
  const int lane = t & 63, wid = t >> 6;
  const int wm = wid >> 1, wn = wid & 1;
  const int lr = lane & 15, lg = lane >> 4;
  const int r0 = tile * 2;

  __shared__ u32x4 lds4[2048];   // 32 KiB: one tap's [128 f][128 c] bf16, XOR-swizzled
  char* lds = (char*)lds4;

  const unsigned short* xbp = xb + (size_t)b * 4096 * 128;
  const unsigned short* wbp = w_ws + (size_t)b * 9 * 16384;

  f32x4 acc[4][4] = {};

  for (int tap = 0; tap < 9; ++tap) {
    const int dh = tap / 3 - 1, dw = tap % 3 - 1;
    __syncthreads();
#pragma unroll
    for (int it = 0; it < 8; ++it) {
      const int i = t + it * 256;              // 16B chunk index, 2048 total
      u32x4 v = *(const u32x4*)(wbp + (size_t)tap * 16384 + i * 8);
      const int f = i >> 4;
      *(u32x4*)(lds + ((i * 16) ^ ((f & 7) << 4))) = v;
    }
    __syncthreads();

    const unsigned short* ap[4];
    bool av[4];
#pragma unroll
    for (int mf = 0; mf < 4; ++mf) {
      const int m = wm * 64 + mf * 16 + lr;
      const int row = r0 + (m >> 6), col = m & 63;
      const int rr = row + dh, cc = col + dw;
      av[mf] = ((unsigned)rr < 64u) && ((unsigned)cc < 64u);
      ap[mf] = xbp + ((size_t)(rr * 64 + cc)) * 128;   // may be OOB-valued; never deref'd
    }
#pragma unroll
    for (int kc = 0; kc < 4; ++kc) {
      bf16x8 afr[4], bfr[4];
      const bf16x8 zero = {};
#pragma unroll
      for (int mf = 0; mf < 4; ++mf)
        afr[mf] = av[mf] ? *(const bf16x8*)(ap[mf] + kc * 32 + lg * 8) : zero;
#pragma unroll
      for (int nf = 0; nf < 4; ++nf) {
        const int f = wn * 64 + nf * 16 + lr;
        const int addr = (f * 256 + kc * 64 + lg * 16) ^ ((f & 7) << 4);
        bfr[nf] = *(const bf16x8*)(lds + addr);
      }
#pragma unroll
      for (int mf = 0; mf < 4; ++mf)
#pragma unroll
        for (int nf = 0; nf < 4; ++nf)
          acc[mf][nf] = __builtin_amdgcn_mfma_f32_16x16x32_bf16(afr[mf], bfr[nf],
                                                                acc[mf][nf], 0, 0, 0);
    }
  }

  // Fused epilogue: relu(acc * inv + beta)
  float af[4], bt[4];
#pragma unroll
  for (int nf = 0; nf < 4; ++nf) {
    const int f = wn * 64 + nf * 16 + lr;
    af[nf] = alpha_ws[f];
    bt[nf] = beta_ws[b * 128 + f];
  }
  float* op = out + (size_t)b * 4096 * 128;
#pragma unroll
  for (int mf = 0; mf < 4; ++mf) {
#pragma unroll
    for (int r = 0; r < 4; ++r) {
      const int m = wm * 64 + mf * 16 + lg * 4 + r;   // C/D: row=(lane>>4)*4+reg
      const int row = r0 + (m >> 6), col = m & 63;
#pragma unroll
      for (int nf = 0; nf < 4; ++nf) {
        const int f = wn * 64 + nf * 16 + lr;          // C/D: col=lane&15
        const float v = acc[mf][nf][r] * af[nf] + bt[nf];
        op[(size_t)(row * 64 + col) * 128 + f] = fmaxf(v, 0.f);
      }
    }
  }
}

extern "C" void kernel_launch(void* const* d_in, const int* in_sizes, int n_in,
                              void* d_out, int out_size, void* d_ws, size_t ws_size,
                              hipStream_t stream) {
  const float* x    = (const float*)d_in[0];   // [32,64,64,128]
  const float* redk = (const float*)d_in[1];   // [128,4]
  const float* attk = (const float*)d_in[2];   // [4,4]
  const float* ck   = (const float*)d_in[3];   // [4,3,3,128,128]
  const float* bias = (const float*)d_in[4];   // [4,128]
  const float* bns  = (const float*)d_in[5];
  const float* bnbb = (const float*)d_in[6];
  const float* bnm  = (const float*)d_in[7];
  const float* bnv  = (const float*)d_in[8];
  float* out = (float*)d_out;

  char* ws = (char*)d_ws;
  unsigned short* xb   = (unsigned short*)ws;                  // 33,554,432 B
  unsigned short* w_ws = (unsigned short*)(ws + 33554432);     //  9,437,184 B
  float* pp       = (float*)(ws + 42991616);                   //    262,144 B
  float* att_ws   = (float*)(ws + 43253760);                   //        512 B
  float* beta_ws  = (float*)(ws + 43254272);                   //     16,384 B
  float* alpha_ws = (float*)(ws + 43270656);                   //        512 B

  k_pool_cvt<<<dim3(16, 32), 256, 0, stream>>>(x, xb, pp);
  k_route<<<32, 128, 0, stream>>>(pp, redk, attk, bias, bns, bnbb, bnm, bnv,
                                  att_ws, beta_ws, alpha_ws);
  k_mixw<<<dim3(9, 32), 256, 0, stream>>>(ck, att_ws, w_ws);
  k_conv<<<dim3(32, 32), 256, 0, stream>>>(xb, w_ws, alpha_ws, beta_ws, out);
}

// Round 2
// 161.818 us; speedup vs baseline: 1.1794x; 1.1794x over previous
//
#include <hip/hip_runtime.h>

typedef short bf16x8 __attribute__((ext_vector_type(8)));
typedef float f32x4 __attribute__((ext_vector_type(4)));
typedef unsigned int u32x4 __attribute__((ext_vector_type(4)));
typedef unsigned short u16x4 __attribute__((ext_vector_type(4)));

__device__ __forceinline__ unsigned short f2bf(float f) {
  unsigned u = __builtin_bit_cast(unsigned, f);
  u = (u + 0x7FFFu + ((u >> 16) & 1u)) >> 16;   // RNE bf16
  return (unsigned short)u;
}

// ---------------- Kernel P: partial pooling sums + x -> bf16 cast ----------
__global__ __launch_bounds__(256) void k_pool_cvt(const float* __restrict__ x,
                                                  unsigned short* __restrict__ xb,
                                                  float* __restrict__ pp) {
  const int slice = blockIdx.x;       // 0..15
  const int b = blockIdx.y;           // 0..31
  const int t = threadIdx.x;
  const int c4 = (t & 31) * 4;
  const int seg = t >> 5;
  const size_t base = ((size_t)b * 4096 + slice * 256 + seg * 32) * 128;
  const float* xp = x + base;
  unsigned short* xbp = xb + base;
  f32x4 s = {0.f, 0.f, 0.f, 0.f};
  for (int p = 0; p < 32; ++p) {
    f32x4 v = *(const f32x4*)(xp + p * 128 + c4);
    s += v;
    u16x4 h;
    h.x = f2bf(v.x); h.y = f2bf(v.y); h.z = f2bf(v.z); h.w = f2bf(v.w);
    *(u16x4*)(xbp + p * 128 + c4) = h;
  }
  __shared__ f32x4 red[256];
  red[t] = s;
  __syncthreads();
  if (t < 32) {
    f32x4 tot = red[t];
#pragma unroll
    for (int g = 1; g < 8; ++g) tot += red[g * 32 + t];
    *(f32x4*)(pp + (size_t)(b * 16 + slice) * 128 + t * 4) = tot;
  }
}

// ---------------- Kernel R: finish pool, attention softmax, fused BN bias --
__global__ __launch_bounds__(128) void k_route(const float* __restrict__ pp,
    const float* __restrict__ redk, const float* __restrict__ attk,
    const float* __restrict__ bias, const float* __restrict__ bns,
    const float* __restrict__ bnb, const float* __restrict__ bnm,
    const float* __restrict__ bnv,
    float* __restrict__ att_ws, float* __restrict__ beta_ws,
    float* __restrict__ alpha_ws) {
  const int b = blockIdx.x, t = threadIdx.x;
  __shared__ float pool[128];
  __shared__ float att[4];
  {
    float s = 0.f;
    for (int i = 0; i < 16; ++i) s += pp[(size_t)(b * 16 + i) * 128 + t];
    pool[t] = s * (1.f / 4096.f);
  }
  __syncthreads();
  if (t == 0) {
    float pr[4];
    for (int r = 0; r < 4; ++r) {
      float s = 0.f;
      for (int c = 0; c < 128; ++c) s += pool[c] * redk[c * 4 + r];
      pr[r] = fmaxf(s, 0.f);
    }
    float lgt[4]; float mx = -1e30f;
    for (int k = 0; k < 4; ++k) {
      float s = 0.f;
      for (int r = 0; r < 4; ++r) s += pr[r] * attk[r * 4 + k];
      lgt[k] = s * (1.f / 30.f);
      mx = fmaxf(mx, lgt[k]);
    }
    float den = 0.f;
    for (int k = 0; k < 4; ++k) { lgt[k] = expf(lgt[k] - mx); den += lgt[k]; }
    for (int k = 0; k < 4; ++k) { att[k] = lgt[k] / den; att_ws[b * 4 + k] = att[k]; }
  }
  __syncthreads();
  {
    float bm = 0.f;
    for (int k = 0; k < 4; ++k) bm += att[k] * bias[k * 128 + t];
    const float inv = bns[t] * rsqrtf(bnv[t] + 1e-5f);
    beta_ws[b * 128 + t] = (bm - bnm[t]) * inv + bnb[t];
    alpha_ws[t] = inv;
  }
}

// ---------------- Kernel W: mix experts, transpose via LDS, PRE-SWIZZLED ---
// w_ws stored chunk j (16B) = logical [f][c] chunk (j ^ ((j>>4)&7)), so k_conv
// can DMA it linearly with global_load_lds and read with the same XOR.
__global__ __launch_bounds__(256) void k_mixw(const float* __restrict__ ck,
                                              const float* __restrict__ att_ws,
                                              unsigned short* __restrict__ w_ws) {
  const int tap = blockIdx.x;   // 0..8
  const int b = blockIdx.y;     // 0..31
  const int t = threadIdx.x;
  const float a0 = att_ws[b * 4 + 0], a1 = att_ws[b * 4 + 1];
  const float a2 = att_ws[b * 4 + 2], a3 = att_ws[b * 4 + 3];
  const float* ckp = ck + (size_t)tap * 16384;
  unsigned short* wp = w_ws + ((size_t)b * 9 + tap) * 16384;
  __shared__ unsigned short lds_t[128 * 136];   // [f][c], pad 8 (16B-aligned rows)
#pragma unroll 4
  for (int it = 0; it < 64; ++it) {
    const int idx = t + it * 256;               // coalesced: o = c*128+f = idx
    const int c = idx >> 7, f = idx & 127;
    float v = a0 * ckp[idx] + a1 * ckp[idx + 147456]
            + a2 * ckp[idx + 2 * 147456] + a3 * ckp[idx + 3 * 147456];
    lds_t[f * 136 + c] = f2bf(v);
  }
  __syncthreads();
#pragma unroll
  for (int it = 0; it < 8; ++it) {
    const int j = t + it * 256;                 // stored 16B chunk
    const int l = j ^ ((j >> 4) & 7);           // logical chunk (involution)
    const int f = l >> 4, c0 = (l & 15) * 8;
    *(bf16x8*)(wp + j * 8) = *(const bf16x8*)(lds_t + f * 136 + c0);
  }
}

// ---------------- Kernel C: 3x3 conv as 9 shifted MFMA GEMMs, pipelined ----
// 512 blocks (16 row-quad tiles x 32 samples), 512 threads = 8 waves (4x2),
// M=256 pixels x N=128 filters, double-buffered LDS weight staging via
// global_load_lds(16B); prefetch tap+1 at top of tap body, drain at tap end.
__device__ __forceinline__ void stage_w(char* dst, const unsigned short* src, int t) {
#pragma unroll
  for (int j = 0; j < 4; ++j) {
    const int i = t + j * 512;                  // 16B chunk, 2048 total
    __builtin_amdgcn_global_load_lds(
        (const __attribute__((address_space(1))) void*)(src + (size_t)i * 8),
        (__attribute__((address_space(3))) void*)(dst + i * 16), 16, 0, 0);
  }
}

__global__ __launch_bounds__(512, 4) void k_conv(const unsigned short* __restrict__ xb,
                                                 const unsigned short* __restrict__ w_ws,
                                                 const float* __restrict__ alpha_ws,
                                                 const float* __restrict__ beta_ws,
                                                 float* __restrict__ out) {
  const int orig = blockIdx.x;
  const int wg = (orig & 7) * 64 + (orig >> 3);   // XCD-chunked, bijective (512%8==0)
  const int b = wg >> 4;          // sample
  const int tile = wg & 15;       // row-quad tile
  const int t = threadIdx.x;
  const int lane = t & 63, wid = t >> 6;
  const int wm = wid >> 1, wn = wid & 1;          // 4 x 2 waves
  const int lr = lane & 15, lg = lane >> 4;
  const int r0 = tile * 4;

  __shared__ char lds[65536];     // 2 x 32 KiB weight buffers

  const unsigned short* xbp = xb + (size_t)b * 4096 * 128;
  const unsigned short* wbp = w_ws + (size_t)b * 9 * 16384;

  f32x4 acc[4][4] = {};

  stage_w(lds, wbp, t);           // tap 0 -> buf 0
  __syncthreads();

  for (int tap = 0; tap < 9; ++tap) {
    char* cb = lds + ((tap & 1) << 15);
    if (tap < 8) stage_w(lds + (((tap & 1) ^ 1) << 15), wbp + (size_t)(tap + 1) * 16384, t);
    const int dh = tap / 3 - 1, dw = tap % 3 - 1;
    const unsigned short* ap[4];
    bool av[4];
#pragma unroll
    for (int mf = 0; mf < 4; ++mf) {
      const int col = mf * 16 + lr;             // pixel col within row
      const int rr = r0 + wm + dh, cc = col + dw;
      av[mf] = ((unsigned)rr < 64u) && ((unsigned)cc < 64u);
      ap[mf] = xbp + ((ptrdiff_t)(rr * 64 + cc)) * 128;
    }
#pragma unroll
    for (int kc = 0; kc < 4; ++kc) {
      bf16x8 afr[4], bfr[4];
      const bf16x8 zero = {};
#pragma unroll
      for (int mf = 0; mf < 4; ++mf)
        afr[mf] = av[mf] ? *(const bf16x8*)(ap[mf] + kc * 32 + lg * 8) : zero;
#pragma unroll
      for (int nf = 0; nf < 4; ++nf) {
        const int f = wn * 64 + nf * 16 + lr;
        const int addr = (f * 256 + kc * 64 + lg * 16) ^ ((f & 7) << 4);
        bfr[nf] = *(const bf16x8*)(cb + addr);
      }
#pragma unroll
      for (int mf = 0; mf < 4; ++mf)
#pragma unroll
        for (int nf = 0; nf < 4; ++nf)
          acc[mf][nf] = __builtin_amdgcn_mfma_f32_16x16x32_bf16(afr[mf], bfr[nf],
                                                                acc[mf][nf], 0, 0, 0);
    }
    __syncthreads();   // drains stage (vmcnt 0) + fences buffer swap
  }

  // Fused epilogue: relu(acc * inv + beta)
  float af[4], bt[4];
#pragma unroll
  for (int nf = 0; nf < 4; ++nf) {
    const int f = wn * 64 + nf * 16 + lr;
    af[nf] = alpha_ws[f];
    bt[nf] = beta_ws[b * 128 + f];
  }
  float* op = out + (size_t)b * 4096 * 128;
  const int row = r0 + wm;
#pragma unroll
  for (int mf = 0; mf < 4; ++mf) {
#pragma unroll
    for (int r = 0; r < 4; ++r) {
      const int col = mf * 16 + lg * 4 + r;     // C/D: row-in-frag = (lane>>4)*4+reg
#pragma unroll
      for (int nf = 0; nf < 4; ++nf) {
        const int f = wn * 64 + nf * 16 + lr;   // C/D: col-in-frag = lane&15
        const float v = acc[mf][nf][r] * af[nf] + bt[nf];
        op[(size_t)(row * 64 + col) * 128 + f] = fmaxf(v, 0.f);
      }
    }
  }
}

extern "C" void kernel_launch(void* const* d_in, const int* in_sizes, int n_in,
                              void* d_out, int out_size, void* d_ws, size_t ws_size,
                              hipStream_t stream) {
  const float* x    = (const float*)d_in[0];
  const float* redk = (const float*)d_in[1];
  const float* attk = (const float*)d_in[2];
  const float* ck   = (const float*)d_in[3];
  const float* bias = (const float*)d_in[4];
  const float* bns  = (const float*)d_in[5];
  const float* bnbb = (const float*)d_in[6];
  const float* bnm  = (const float*)d_in[7];
  const float* bnv  = (const float*)d_in[8];
  float* out = (float*)d_out;

  char* ws = (char*)d_ws;
  unsigned short* xb   = (unsigned short*)ws;                  // 33,554,432 B
  unsigned short* w_ws = (unsigned short*)(ws + 33554432);     //  9,437,184 B
  float* pp       = (float*)(ws + 42991616);                   //    262,144 B
  float* att_ws   = (float*)(ws + 43253760);
  float* beta_ws  = (float*)(ws + 43254272);
  float* alpha_ws = (float*)(ws + 43270656);

  k_pool_cvt<<<dim3(16, 32), 256, 0, stream>>>(x, xb, pp);
  k_route<<<32, 128, 0, stream>>>(pp, redk, attk, bias, bns, bnbb, bnm, bnv,
                                  att_ws, beta_ws, alpha_ws);
  k_mixw<<<dim3(9, 32), 256, 0, stream>>>(ck, att_ws, w_ws);
  k_conv<<<512, 512, 0, stream>>>(xb, w_ws, alpha_ws, beta_ws, out);
}

// Round 3
// 83.152 us; speedup vs baseline: 2.2952x; 1.9460x over previous
//
#include <hip/hip_runtime.h>

typedef short bf16x8 __attribute__((ext_vector_type(8)));
typedef float f32x4 __attribute__((ext_vector_type(4)));
typedef unsigned int u32x4 __attribute__((ext_vector_type(4)));
typedef unsigned short u16x4 __attribute__((ext_vector_type(4)));

__device__ __forceinline__ unsigned short f2bf(float f) {
  unsigned u = __builtin_bit_cast(unsigned, f);
  u = (u + 0x7FFFu + ((u >> 16) & 1u)) >> 16;   // RNE bf16
  return (unsigned short)u;
}

// ---------------- Kernel P: partial pooling sums + x -> bf16 cast ----------
__global__ __launch_bounds__(256) void k_pool_cvt(const float* __restrict__ x,
                                                  unsigned short* __restrict__ xb,
                                                  float* __restrict__ pp) {
  const int slice = blockIdx.x;       // 0..15
  const int b = blockIdx.y;           // 0..31
  const int t = threadIdx.x;
  const int c4 = (t & 31) * 4;
  const int seg = t >> 5;
  const size_t base = ((size_t)b * 4096 + slice * 256 + seg * 32) * 128;
  const float* xp = x + base;
  unsigned short* xbp = xb + base;
  f32x4 s = {0.f, 0.f, 0.f, 0.f};
  for (int p = 0; p < 32; ++p) {
    f32x4 v = *(const f32x4*)(xp + p * 128 + c4);
    s += v;
    u16x4 h;
    h.x = f2bf(v.x); h.y = f2bf(v.y); h.z = f2bf(v.z); h.w = f2bf(v.w);
    *(u16x4*)(xbp + p * 128 + c4) = h;
  }
  __shared__ f32x4 red[256];
  red[t] = s;
  __syncthreads();
  if (t < 32) {
    f32x4 tot = red[t];
#pragma unroll
    for (int g = 1; g < 8; ++g) tot += red[g * 32 + t];
    *(f32x4*)(pp + (size_t)(b * 16 + slice) * 128 + t * 4) = tot;
  }
}

// ---------------- Kernel R: finish pool, attention softmax, fused BN bias --
__global__ __launch_bounds__(128) void k_route(const float* __restrict__ pp,
    const float* __restrict__ redk, const float* __restrict__ attk,
    const float* __restrict__ bias, const float* __restrict__ bns,
    const float* __restrict__ bnb, const float* __restrict__ bnm,
    const float* __restrict__ bnv,
    float* __restrict__ att_ws, float* __restrict__ beta_ws,
    float* __restrict__ alpha_ws) {
  const int b = blockIdx.x, t = threadIdx.x;
  __shared__ float pool[128];
  __shared__ float att[4];
  {
    float s = 0.f;
    for (int i = 0; i < 16; ++i) s += pp[(size_t)(b * 16 + i) * 128 + t];
    pool[t] = s * (1.f / 4096.f);
  }
  __syncthreads();
  if (t == 0) {
    float pr[4];
    for (int r = 0; r < 4; ++r) {
      float s = 0.f;
      for (int c = 0; c < 128; ++c) s += pool[c] * redk[c * 4 + r];
      pr[r] = fmaxf(s, 0.f);
    }
    float lgt[4]; float mx = -1e30f;
    for (int k = 0; k < 4; ++k) {
      float s = 0.f;
      for (int r = 0; r < 4; ++r) s += pr[r] * attk[r * 4 + k];
      lgt[k] = s * (1.f / 30.f);
      mx = fmaxf(mx, lgt[k]);
    }
    float den = 0.f;
    for (int k = 0; k < 4; ++k) { lgt[k] = expf(lgt[k] - mx); den += lgt[k]; }
    for (int k = 0; k < 4; ++k) { att[k] = lgt[k] / den; att_ws[b * 4 + k] = att[k]; }
  }
  __syncthreads();
  {
    float bm = 0.f;
    for (int k = 0; k < 4; ++k) bm += att[k] * bias[k * 128 + t];
    const float inv = bns[t] * rsqrtf(bnv[t] + 1e-5f);
    beta_ws[b * 128 + t] = (bm - bnm[t]) * inv + bnb[t];
    alpha_ws[t] = inv;
  }
}

// ---------------- Kernel W: mix experts -> w_ws[b][h][tap] 16KB slabs ------
// Slab = [128 f][64 c] bf16, PRE-SWIZZLED: 16B chunk holding (f, c-oct o) is
// stored at chunk index f*8 + (o ^ (f&7)), so k_conv DMAs linearly and reads
// with addr ^ ((f&7)<<4).
__global__ __launch_bounds__(256) void k_mixw(const float* __restrict__ ck,
                                              const float* __restrict__ att_ws,
                                              unsigned short* __restrict__ w_ws) {
  const int tap = blockIdx.x;   // 0..8
  const int b = blockIdx.y;     // 0..31
  const int t = threadIdx.x;
  const float a0 = att_ws[b * 4 + 0], a1 = att_ws[b * 4 + 1];
  const float a2 = att_ws[b * 4 + 2], a3 = att_ws[b * 4 + 3];
  const float* ckp = ck + (size_t)tap * 16384;
  __shared__ unsigned short lds_t[128 * 136];   // [f][c], padded row
#pragma unroll 4
  for (int it = 0; it < 16; ++it) {
    const int i4 = t + it * 256;          // f32x4 index (4096 total)
    const int idx = i4 * 4;               // c = idx>>7, f = idx&127 (4-aligned)
    const int c = idx >> 7, f = idx & 127;
    f32x4 v0 = *(const f32x4*)(ckp + idx);
    f32x4 v1 = *(const f32x4*)(ckp + idx + 147456);
    f32x4 v2 = *(const f32x4*)(ckp + idx + 2 * 147456);
    f32x4 v3 = *(const f32x4*)(ckp + idx + 3 * 147456);
#pragma unroll
    for (int e = 0; e < 4; ++e)
      lds_t[(f + e) * 136 + c] = f2bf(a0 * v0[e] + a1 * v1[e] + a2 * v2[e] + a3 * v3[e]);
  }
  __syncthreads();
#pragma unroll
  for (int it = 0; it < 8; ++it) {
    const int m = t + it * 256;           // 2048 chunks total
    const int f = m >> 4, oo = m & 15, h = oo >> 3, o = oo & 7;
    unsigned short* dst = w_ws + ((size_t)b * 18 + h * 9 + tap) * 8192
                        + (size_t)(f * 8 + (o ^ (f & 7))) * 8;
    *(bf16x8*)dst = *(const bf16x8*)(lds_t + f * 136 + oo * 8);
  }
}

// ---------------- Kernel C: 3x3 conv, x-tile + weights in LDS --------------
// 512 blocks (32 samples x 16 row-quads), 512 thr = 8 waves (wm 0..3 x wn 0..1).
// M = 4 rows x 64 cols, N = 128 f. K split: 2 ch-halves x 9 taps x 2 kc.
// LDS 80 KB: xt 48 KB (6 rows x 64 px x 64 ch, XOR-swizzled via pre-swizzled
// global src) + 2 x 16 KB weight slabs (pre-swizzled by k_mixw). 2 blocks/CU.
__device__ __forceinline__ void stage_w16(char* dst, const unsigned short* src, int t) {
#pragma unroll
  for (int j = 0; j < 2; ++j) {
    const int i = t + j * 512;            // 16B chunk, 1024 total
    __builtin_amdgcn_global_load_lds(
        (const __attribute__((address_space(1))) void*)(src + (size_t)i * 8),
        (__attribute__((address_space(3))) void*)(dst + i * 16), 16, 0, 0);
  }
}

__device__ __forceinline__ void stage_x_half(char* xt, const unsigned short* xbp,
                                             int r0, int h, int t) {
  const int pix = t >> 3;                             // 0..63
  const int oct = (t & 7) ^ ((t >> 3) & 7);           // pre-swizzled source oct
#pragma unroll
  for (int j = 0; j < 6; ++j) {
    const int rr = r0 - 1 + j;
    char* dst = xt + j * 8192 + t * 16;               // linear LDS dest
    if ((unsigned)rr < 64u) {
      __builtin_amdgcn_global_load_lds(
          (const __attribute__((address_space(1))) void*)
              (xbp + ((size_t)(rr * 64 + pix)) * 128 + h * 64 + oct * 8),
          (__attribute__((address_space(3))) void*)dst, 16, 0, 0);
    } else {
      *(u32x4*)dst = (u32x4){0, 0, 0, 0};             // zero padding row
    }
  }
}

__global__ __launch_bounds__(512, 4) void k_conv(const unsigned short* __restrict__ xb,
                                                 const unsigned short* __restrict__ w_ws,
                                                 const float* __restrict__ alpha_ws,
                                                 const float* __restrict__ beta_ws,
                                                 float* __restrict__ out) {
  extern __shared__ char lds[];           // 81920 B
  char* xt = lds;                         // 49152 B
  char* wlds = lds + 49152;               // 2 x 16384 B

  const int orig = blockIdx.x;
  const int wg = (orig & 7) * 64 + (orig >> 3);   // XCD-chunked, bijective
  const int b = wg >> 4;
  const int tile = wg & 15;
  const int t = threadIdx.x;
  const int lane = t & 63, wid = t >> 6;
  const int wm = wid >> 1, wn = wid & 1;          // wave -> (row, f-half)
  const int lr = lane & 15, lg = lane >> 4;
  const int r0 = tile * 4;

  const unsigned short* xbp = xb + (size_t)b * 4096 * 128;
  const unsigned short* wsrc = w_ws + (size_t)b * 18 * 8192;

  f32x4 acc[4][4] = {};
  const bf16x8 zero = {};

  stage_x_half(xt, xbp, r0, 0, t);
  stage_w16(wlds, wsrc, t);
  __syncthreads();

  for (int s = 0; s < 18; ++s) {
    const int tap = s % 9;
    char* cb = wlds + ((s & 1) << 14);
    if (s < 17) stage_w16(wlds + (((s & 1) ^ 1) << 14), wsrc + (size_t)(s + 1) * 8192, t);
    const int dh = tap / 3 - 1, dw = tap % 3 - 1;
    const int jrow = wm + dh + 1;                 // 0..5 within xt
#pragma unroll
    for (int kc = 0; kc < 2; ++kc) {
      bf16x8 afr[4], bfr[4];
#pragma unroll
      for (int mf = 0; mf < 4; ++mf) {
        const int col = mf * 16 + lr + dw;        // -1..64
        const int a = ((jrow * 64 + col) * 128 + kc * 64 + lg * 16) ^ ((col & 7) << 4);
        afr[mf] = ((unsigned)col < 64u) ? *(const bf16x8*)(xt + a) : zero;
      }
#pragma unroll
      for (int nf = 0; nf < 4; ++nf) {
        const int f = wn * 64 + nf * 16 + lr;
        const int a = (f * 128 + kc * 64 + lg * 16) ^ ((f & 7) << 4);
        bfr[nf] = *(const bf16x8*)(cb + a);
      }
#pragma unroll
      for (int mf = 0; mf < 4; ++mf)
#pragma unroll
        for (int nf = 0; nf < 4; ++nf)
          acc[mf][nf] = __builtin_amdgcn_mfma_f32_16x16x32_bf16(afr[mf], bfr[nf],
                                                                acc[mf][nf], 0, 0, 0);
    }
    __syncthreads();                              // drain stage + fence swap
    if (s == 8) {                                 // channel-half switch
      stage_x_half(xt, xbp, r0, 1, t);
      __syncthreads();
    }
  }

  // Fused epilogue: relu(acc * inv + beta)
  float af[4], bt[4];
#pragma unroll
  for (int nf = 0; nf < 4; ++nf) {
    const int f = wn * 64 + nf * 16 + lr;
    af[nf] = alpha_ws[f];
    bt[nf] = beta_ws[b * 128 + f];
  }
  float* op = out + (size_t)b * 4096 * 128;
  const int row = r0 + wm;
#pragma unroll
  for (int mf = 0; mf < 4; ++mf) {
#pragma unroll
    for (int r = 0; r < 4; ++r) {
      const int col = mf * 16 + lg * 4 + r;       // C/D: row-in-frag = lg*4+reg
#pragma unroll
      for (int nf = 0; nf < 4; ++nf) {
        const int f = wn * 64 + nf * 16 + lr;     // C/D: col-in-frag = lane&15
        const float v = acc[mf][nf][r] * af[nf] + bt[nf];
        op[(size_t)(row * 64 + col) * 128 + f] = fmaxf(v, 0.f);
      }
    }
  }
}

extern "C" void kernel_launch(void* const* d_in, const int* in_sizes, int n_in,
                              void* d_out, int out_size, void* d_ws, size_t ws_size,
                              hipStream_t stream) {
  const float* x    = (const float*)d_in[0];
  const float* redk = (const float*)d_in[1];
  const float* attk = (const float*)d_in[2];
  const float* ck   = (const float*)d_in[3];
  const float* bias = (const float*)d_in[4];
  const float* bns  = (const float*)d_in[5];
  const float* bnbb = (const float*)d_in[6];
  const float* bnm  = (const float*)d_in[7];
  const float* bnv  = (const float*)d_in[8];
  float* out = (float*)d_out;

  char* ws = (char*)d_ws;
  unsigned short* xb   = (unsigned short*)ws;                  // 33,554,432 B
  unsigned short* w_ws = (unsigned short*)(ws + 33554432);     //  9,437,184 B
  float* pp       = (float*)(ws + 42991616);                   //    262,144 B
  float* att_ws   = (float*)(ws + 43253760);
  float* beta_ws  = (float*)(ws + 43254272);
  float* alpha_ws = (float*)(ws + 43270656);

  k_pool_cvt<<<dim3(16, 32), 256, 0, stream>>>(x, xb, pp);
  k_route<<<32, 128, 0, stream>>>(pp, redk, attk, bias, bns, bnbb, bnm, bnv,
                                  att_ws, beta_ws, alpha_ws);
  k_mixw<<<dim3(9, 32), 256, 0, stream>>>(ck, att_ws, w_ws);
  k_conv<<<512, 512, 81920, stream>>>(xb, w_ws, alpha_ws, beta_ws, out);
}